// Round 7
// baseline (98.797 us; speedup 1.0000x reference)
//
#include <hip/hip_runtime.h>
#include <hip/hip_bf16.h>
#include <math.h>

typedef __attribute__((ext_vector_type(8))) short bf16x8;
typedef __attribute__((ext_vector_type(4))) float f32x4;

#define NSC    8
#define SLEN   4096
#define FEAT   64
#define CHUNK_B 8192      // one 64-row chunk of sigT2, bytes
#define NQ     258        // q = 2*c_old + tw <= 2*127+3 = 257
#define ATAB_B (NQ * 8 * 1024)   // 2,113,536 bytes

// L = int(64 * 64^(i/7)) from np.logspace(0, log10(64), 8)
constexpr int L_[NSC]    = {64, 115, 210, 380, 689, 1248, 2261, 4096};
constexpr int CACT_[NSC] = {3, 5, 8, 13, 23, 40, 72, 129};  // last active c_old

struct WavP { float step[NSC]; float isq[NSC]; };

// ---------------- kernel 1: build MFMA-fragment-ordered A table -----------------
// Atab[q][s][l][j] = w~_s[16q - 32 + (l&15) - 8*(l>>4) - j], zero outside [0,L_s).
// w~(k) = interp(mother, k*step) * (1/sqrt scale) * scale_weight  (jnp.interp match)
__global__ void k_build_atab(const float* __restrict__ mw, const float* __restrict__ sw,
                             __hip_bfloat16* __restrict__ at, WavP wp)
{
  int e = blockIdx.x * 256 + threadIdx.x;       // e < NQ*8*512
  int j = e & 7, l = (e >> 3) & 63, s = (e >> 9) & 7, q = e >> 12;
  int k = 16 * q - 32 + (l & 15) - 8 * (l >> 4) - j;
  float val = 0.f;
  if (k >= 0 && k < L_[s]) {
    float pos = (float)k * wp.step[s];
    int ii = (int)pos;
    float r;
    if (ii >= 63) r = mw[s * 64 + 63];
    else {
      float a = mw[s * 64 + ii];
      r = fmaf(pos - (float)ii, mw[s * 64 + ii + 1] - a, a);
    }
    val = r * wp.isq[s] * sw[s];
  }
  at[e] = __float2bfloat16(val);
}

// ---------------- kernel 2: signal f32 [b][r][f] -> bf16 FRAGMENT-ORDERED -------
// Per 64-row chunk (b*64+rb): element e = h*2048 + n*512 + l*8 + i holds
// sig[r = rb*64 + h*32 + (l>>4)*8 + i][f = n*16 + (l&15)].
__global__ __launch_bounds__(256) void k_transpose(const float* __restrict__ sig,
                                                   __hip_bfloat16* __restrict__ sigT2)
{
  __shared__ float t[4096];                 // flat [r][f], XOR-swizzled banks
  const int tid = threadIdx.x;
  const float* sp = sig + (size_t)blockIdx.x * 4096;
  for (int idx = tid; idx < 4096; idx += 256) {
    int r = idx >> 6, f = idx & 63;
    t[(r << 6) + (f ^ ((r & 7) << 3))] = sp[idx];
  }
  __syncthreads();
  __hip_bfloat16* op = sigT2 + (size_t)blockIdx.x * 4096;
  for (int e = tid; e < 4096; e += 256) {
    int h = e >> 11, n = (e >> 9) & 3, l = (e >> 3) & 63, i = e & 7;
    int f = n * 16 + (l & 15);
    int r = h * 32 + (l >> 4) * 8 + i;
    op[e] = __float2bfloat16(t[(r << 6) + (f ^ ((r & 7) << 3))]);
  }
}

// ---------------- kernel 3: banded-Toeplitz MFMA convolution, ZERO LDS ----------
// Block = 256 thr = 4 waves; block owns (b, 64-t tile); wave tw owns rows t0+16tw..+15.
// A and B both stream from global (L1/L2) as fully-coalesced 1KB wave64 dwordx4
// loads; B double-buffered one k-step ahead. No LDS, no barriers, no conflicts.
__global__ __launch_bounds__(256, 2) void k_wavelet_mfma(
    const __hip_bfloat16* __restrict__ sigT2,
    const __hip_bfloat16* __restrict__ atab,
    float* __restrict__ out)
{
  const int tid = threadIdx.x;
  const int bid = blockIdx.x;
  const int tt  = 63 - (bid >> 4);        // heavy (large t0) tiles first
  const int b   = bid & 15;
  const int t0  = tt * 64;
  const int tw  = tid >> 6;               // wave id
  const int l   = tid & 63;               // lane
  const int fl  = tid & 15;               // lane&15: A-row / B-col / D-col
  const int g   = (tid >> 4) & 3;         // lane>>4: k-group / D-row-group

  const int C = tt + 1;                   // chunks: rows [64(tt-c), +63], c=0..C-1
  const char* cb = (const char*)sigT2 + ((size_t)(b * 64 + tt)) * CHUNK_B
                   + (size_t)l * 16;
  // per-wave A base: frag (c_old, s) at aw + c_old*16384 + s*1024
  const char* aw = (const char*)atab + tw * 8192 + (size_t)l * 16;

  f32x4 acc[NSC][4];
  const f32x4 z = {0.f, 0.f, 0.f, 0.f};
  #pragma unroll
  for (int s = 0; s < NSC; ++s)
    #pragma unroll
    for (int n = 0; n < 4; ++n) acc[s][n] = z;

  // B-frag set for one k-step: chunk c, half h (h=1: rows +32..63, h=0: rows +0..31)
  auto loadB = [&](int c, int h, bf16x8* B) {
    const char* p = cb - (size_t)c * CHUNK_B + h * 4096;
    #pragma unroll
    for (int n = 0; n < 4; ++n)
      B[n] = *(const bf16x8*)(p + n * 1024);
  };

  auto compute = [&](int c_old, const bf16x8* Bf) {
    const char* pa = aw + (size_t)c_old * 16384;
    bf16x8 Af[NSC];
    #pragma unroll
    for (int s = 0; s < NSC; ++s)
      if (c_old <= CACT_[s])
        Af[s] = *(const bf16x8*)(pa + s * 1024);
    __builtin_amdgcn_s_setprio(1);
    #pragma unroll
    for (int s = NSC - 1; s >= 0; --s) {
      if (c_old <= CACT_[s]) {            // wave-uniform; static indices
        acc[s][0] = __builtin_amdgcn_mfma_f32_16x16x32_bf16(Af[s], Bf[0], acc[s][0], 0, 0, 0);
        acc[s][1] = __builtin_amdgcn_mfma_f32_16x16x32_bf16(Af[s], Bf[1], acc[s][1], 0, 0, 0);
        acc[s][2] = __builtin_amdgcn_mfma_f32_16x16x32_bf16(Af[s], Bf[2], acc[s][2], 0, 0, 0);
        acc[s][3] = __builtin_amdgcn_mfma_f32_16x16x32_bf16(Af[s], Bf[3], acc[s][3], 0, 0, 0);
      }
    }
    __builtin_amdgcn_s_setprio(0);
  };

  bf16x8 B0[4], B1[4];
  loadB(0, 1, B0);                        // (c=0, h=1) = c_old 0

  for (int c = 0; c < C; ++c) {
    loadB(c, 0, B1);                      // next step's B in flight
    compute(2 * c, B0);                   // chunk c, upper 32 rows
    loadB(c + 1, 1, B0);                  // next chunk's B in flight
    // (dangles 4KB below sigT2 on the last iter -> lands in d_ws gap, unused)
    compute(2 * c + 1, B1);               // chunk c, lower 32 rows
  }

  // epilogue: D row = 4*g + reg, col = 16n + fl
  const int trow = t0 + tw * 16 + g * 4;
  float* ob = out + (size_t)b * NSC * SLEN * FEAT;
  #pragma unroll
  for (int s = 0; s < NSC; ++s) {
    float* os = ob + (size_t)s * SLEN * FEAT;
    #pragma unroll
    for (int n = 0; n < 4; ++n)
      #pragma unroll
      for (int r = 0; r < 4; ++r)
        os[(size_t)(trow + r) * FEAT + n * 16 + fl] = acc[s][n][r];
  }
}

extern "C" void kernel_launch(void* const* d_in, const int* in_sizes, int n_in,
                              void* d_out, int out_size, void* d_ws, size_t ws_size,
                              hipStream_t stream) {
  const float* sig = (const float*)d_in[0];
  const float* mw  = (const float*)d_in[1];
  const float* sw  = (const float*)d_in[2];
  float*       out = (float*)d_out;

  // workspace: [0, ATAB_B) A-fragment table bf16; [0x220000, +8MB) sigT2 bf16
  __hip_bfloat16* atab  = (__hip_bfloat16*)d_ws;
  __hip_bfloat16* sigT2 = (__hip_bfloat16*)((char*)d_ws + 0x220000);

  // runtime per-scale floats (same double math as np.logspace path)
  WavP wp;
  const double lg = log10(64.0), st = lg / 7.0;
  for (int i = 0; i < NSC; ++i) {
    double y = (i == 7) ? lg : (double)i * st;
    double s = pow(10.0, y);
    wp.step[i] = (float)(63.0 / (double)(L_[i] - 1));
    wp.isq[i]  = (float)(1.0 / sqrt(s));
  }

  k_build_atab<<<NQ * 8 * 512 / 256, 256, 0, stream>>>(mw, sw, atab, wp);
  k_transpose<<<1024, 256, 0, stream>>>(sig, sigT2);
  k_wavelet_mfma<<<1024, 256, 0, stream>>>(sigT2, atab, out);
}

// Round 8
// 90.068 us; speedup vs baseline: 1.0969x; 1.0969x over previous
//
#include <hip/hip_runtime.h>
#include <hip/hip_bf16.h>
#include <math.h>

typedef __attribute__((ext_vector_type(8))) short bf16x8;
typedef __attribute__((ext_vector_type(4))) float f32x4;

#define NSC    8
#define SLEN   4096
#define FEAT   64
#define NQ     264               // q = 2*c_old + tw; worst case 257, +overshoot pad
#define ATAB_B (NQ * 8 * 1024)   // 2,162,688 bytes

// L = int(64 * 64^(i/7)) from np.logspace(0, log10(64), 8)
constexpr int L_[NSC]    = {64, 115, 210, 380, 689, 1248, 2261, 4096};
constexpr int CACT_[NSC] = {3, 5, 8, 13, 23, 40, 72, 129};  // last active c_old

struct WavP { float step[NSC]; float isq[NSC]; };

// ---------------- kernel 1: build MFMA-fragment-ordered A table -----------------
// Atab[q][s][l][j] = w~_s[16q - 32 + (l&15) - 8*(l>>4) - j], zero outside [0,L_s).
// w~(k) = interp(mother, k*step) * (1/sqrt scale) * scale_weight  (jnp.interp match)
__global__ void k_build_atab(const float* __restrict__ mw, const float* __restrict__ sw,
                             __hip_bfloat16* __restrict__ at, WavP wp)
{
  int e = blockIdx.x * 256 + threadIdx.x;       // e < NQ*8*512
  int j = e & 7, l = (e >> 3) & 63, s = (e >> 9) & 7, q = e >> 12;
  int k = 16 * q - 32 + (l & 15) - 8 * (l >> 4) - j;
  float val = 0.f;
  if (k >= 0 && k < L_[s]) {
    float pos = (float)k * wp.step[s];
    int ii = (int)pos;
    float r;
    if (ii >= 63) r = mw[s * 64 + 63];
    else {
      float a = mw[s * 64 + ii];
      r = fmaf(pos - (float)ii, mw[s * 64 + ii + 1] - a, a);
    }
    val = r * wp.isq[s] * sw[s];
  }
  at[e] = __float2bfloat16(val);
}

// ---------------- kernel 2: signal f32 [b][r][f] -> bf16 FRAGMENT-ORDERED -------
// Per 64-row chunk (b*64+rb): element e = h*2048 + n*512 + l*8 + i holds
// sig[r = rb*64 + h*32 + (l>>4)*8 + i][f = n*16 + (l&15)].
__global__ __launch_bounds__(256) void k_transpose(const float* __restrict__ sig,
                                                   __hip_bfloat16* __restrict__ sigT2)
{
  __shared__ float t[4096];                 // flat [r][f], XOR-swizzled banks
  const int tid = threadIdx.x;
  const float* sp = sig + (size_t)blockIdx.x * 4096;
  for (int idx = tid; idx < 4096; idx += 256) {
    int r = idx >> 6, f = idx & 63;
    t[(r << 6) + (f ^ ((r & 7) << 3))] = sp[idx];
  }
  __syncthreads();
  __hip_bfloat16* op = sigT2 + (size_t)blockIdx.x * 4096;
  for (int e = tid; e < 4096; e += 256) {
    int h = e >> 11, n = (e >> 9) & 3, l = (e >> 3) & 63, i = e & 7;
    int f = n * 16 + (l & 15);
    int r = h * 32 + (l >> 4) * 8 + i;
    op[e] = __float2bfloat16(t[(r << 6) + (f ^ ((r & 7) << 3))]);
  }
}

// ---------------- kernel 3 helpers: 4-scale pass, A+B both prefetched -----------
template<int SB>
__device__ __forceinline__ void loadA4(const char* aw, int c_old, bf16x8* A) {
  #pragma unroll
  for (int i = 0; i < 4; ++i)
    if (c_old <= CACT_[SB + i])
      A[i] = *(const bf16x8*)(aw + (size_t)c_old * 16384 + (SB + i) * 1024);
}

__device__ __forceinline__ void loadB4(const char* cb2, int c_old, bf16x8* B) {
  const char* p = cb2 - (size_t)c_old * 4096;
  #pragma unroll
  for (int n = 0; n < 4; ++n)
    B[n] = *(const bf16x8*)(p + n * 1024);
}

template<int SB>
__device__ __forceinline__ void stepMFMA(int c_old, const bf16x8* A, const bf16x8* B,
                                         f32x4 (*acc)[4]) {
  __builtin_amdgcn_s_setprio(1);
  #pragma unroll
  for (int i = 3; i >= 0; --i) {
    if (c_old <= CACT_[SB + i]) {          // wave-uniform; static indices
      acc[i][0] = __builtin_amdgcn_mfma_f32_16x16x32_bf16(A[i], B[0], acc[i][0], 0, 0, 0);
      acc[i][1] = __builtin_amdgcn_mfma_f32_16x16x32_bf16(A[i], B[1], acc[i][1], 0, 0, 0);
      acc[i][2] = __builtin_amdgcn_mfma_f32_16x16x32_bf16(A[i], B[2], acc[i][2], 0, 0, 0);
      acc[i][3] = __builtin_amdgcn_mfma_f32_16x16x32_bf16(A[i], B[3], acc[i][3], 0, 0, 0);
    }
  }
  __builtin_amdgcn_s_setprio(0);
}

template<int SB>
__device__ __forceinline__ void run_pass(const char* aw, const char* cb2, int nsteps,
                                         float* ob, int trow, int fl) {
  f32x4 acc[4][4];
  const f32x4 z = {0.f, 0.f, 0.f, 0.f};
  #pragma unroll
  for (int i = 0; i < 4; ++i)
    #pragma unroll
    for (int n = 0; n < 4; ++n) acc[i][n] = z;

  bf16x8 A0[4], A1[4], B0[4], B1[4];
  loadA4<SB>(aw, 0, A0);
  loadB4(cb2, 0, B0);

  for (int st = 0; st < nsteps; st += 2) {       // nsteps is even
    loadA4<SB>(aw, st + 1, A1);                  // next step in flight
    loadB4(cb2, st + 1, B1);
    stepMFMA<SB>(st, A0, B0, acc);
    loadA4<SB>(aw, st + 2, A0);                  // step after next in flight
    loadB4(cb2, st + 2, B0);                     // (overshoot lands in d_ws pads)
    stepMFMA<SB>(st + 1, A1, B1, acc);
  }

  #pragma unroll
  for (int i = 0; i < 4; ++i) {
    float* os = ob + (size_t)(SB + i) * SLEN * FEAT;
    #pragma unroll
    for (int n = 0; n < 4; ++n)
      #pragma unroll
      for (int r = 0; r < 4; ++r)
        os[(size_t)(trow + r) * FEAT + n * 16 + fl] = acc[i][n][r];
  }
}

// ---------------- kernel 3: banded-Toeplitz MFMA convolution, ZERO LDS ----------
// Block = 256 thr = 4 waves; block owns (b, 64-t tile); wave tw owns rows t0+16tw..+15.
// Two sequential 4-scale passes (acc 64 VGPR each) -> 3 waves/SIMD occupancy.
// A and B both fully-coalesced 1KB wave64 global loads, both prefetched 1 step ahead.
__global__ __launch_bounds__(256, 3) void k_wavelet_mfma(
    const __hip_bfloat16* __restrict__ sigT2,
    const __hip_bfloat16* __restrict__ atab,
    float* __restrict__ out)
{
  const int tid = threadIdx.x;
  const int bid = blockIdx.x;
  const int tt  = 63 - (bid >> 4);        // heavy (large t0) tiles first
  const int b   = bid & 15;
  const int t0  = tt * 64;
  const int tw  = tid >> 6;               // wave id
  const int l   = tid & 63;               // lane
  const int fl  = tid & 15;               // lane&15: A-row / B-col / D-col
  const int g   = (tid >> 4) & 3;         // lane>>4: k-group / D-row-group

  const int C = tt + 1;
  // A frag (c_old, s) at aw + c_old*16384 + s*1024  (q = 2*c_old + tw)
  const char* aw  = (const char*)atab + tw * 8192 + (size_t)l * 16;
  // B frag (c_old, n) at cb2 - c_old*4096 + n*1024  (half-chunks count down)
  const char* cb2 = (const char*)sigT2 + ((size_t)((b * 64 + tt) * 2 + 1)) * 4096
                    + (size_t)l * 16;

  float* ob = out + (size_t)b * NSC * SLEN * FEAT;
  const int trow = t0 + tw * 16 + g * 4;  // D row = 4*g + reg, col = 16n + fl

  run_pass<4>(aw, cb2, 2 * C, ob, trow, fl);                 // heavy scales 4-7
  run_pass<0>(aw, cb2, min(2 * C, 14), ob, trow, fl);        // light scales 0-3
}

extern "C" void kernel_launch(void* const* d_in, const int* in_sizes, int n_in,
                              void* d_out, int out_size, void* d_ws, size_t ws_size,
                              hipStream_t stream) {
  const float* sig = (const float*)d_in[0];
  const float* mw  = (const float*)d_in[1];
  const float* sw  = (const float*)d_in[2];
  float*       out = (float*)d_out;

  // workspace: [0, ATAB_B) A-fragment table bf16; [0x240000, +8MB) sigT2 bf16
  __hip_bfloat16* atab  = (__hip_bfloat16*)d_ws;
  __hip_bfloat16* sigT2 = (__hip_bfloat16*)((char*)d_ws + 0x240000);

  // runtime per-scale floats (same double math as np.logspace path)
  WavP wp;
  const double lg = log10(64.0), st = lg / 7.0;
  for (int i = 0; i < NSC; ++i) {
    double y = (i == 7) ? lg : (double)i * st;
    double s = pow(10.0, y);
    wp.step[i] = (float)(63.0 / (double)(L_[i] - 1));
    wp.isq[i]  = (float)(1.0 / sqrt(s));
  }

  k_build_atab<<<NQ * 16, 256, 0, stream>>>(mw, sw, atab, wp);
  k_transpose<<<1024, 256, 0, stream>>>(sig, sigT2);
  k_wavelet_mfma<<<1024, 256, 0, stream>>>(sigT2, atab, out);
}

// Round 9
// 86.521 us; speedup vs baseline: 1.1419x; 1.0410x over previous
//
#include <hip/hip_runtime.h>
#include <hip/hip_bf16.h>
#include <math.h>

typedef __attribute__((ext_vector_type(8))) short bf16x8;
typedef __attribute__((ext_vector_type(4))) float f32x4;

#define NSC    8
#define SLEN   4096
#define FEAT   64
#define NQ     264               // q = 2*c_old + tw; CACT-guarded max 261
#define ATAB_B (NQ * 8 * 1024)

// L = int(64 * 64^(i/7)) from np.logspace(0, log10(64), 8)
constexpr int L_[NSC]    = {64, 115, 210, 380, 689, 1248, 2261, 4096};
constexpr int CACT_[NSC] = {3, 5, 8, 13, 23, 40, 72, 129};  // last active c_old

struct WavP { float step[NSC]; float isq[NSC]; };

// ---------------- kernel 1: build MFMA-fragment-ordered A table -----------------
// Atab[q][s][l][j] = w~_s[16q - 32 + (l&15) - 8*(l>>4) - j], zero outside [0,L_s).
__global__ void k_build_atab(const float* __restrict__ mw, const float* __restrict__ sw,
                             __hip_bfloat16* __restrict__ at, WavP wp)
{
  int e = blockIdx.x * 256 + threadIdx.x;       // e < NQ*4096
  int j = e & 7, l = (e >> 3) & 63, s = (e >> 9) & 7, q = e >> 12;
  int k = 16 * q - 32 + (l & 15) - 8 * (l >> 4) - j;
  float val = 0.f;
  if (k >= 0 && k < L_[s]) {
    float pos = (float)k * wp.step[s];
    int ii = (int)pos;
    float r;
    if (ii >= 63) r = mw[s * 64 + 63];
    else {
      float a = mw[s * 64 + ii];
      r = fmaf(pos - (float)ii, mw[s * 64 + ii + 1] - a, a);
    }
    val = r * wp.isq[s] * sw[s];
  }
  at[e] = __float2bfloat16(val);
}

// ---------------- kernel 2: signal f32 [b][r][f] -> bf16 FRAGMENT-ORDERED -------
// Per 64-row chunk (b*64+rb): element e = h*2048 + n*512 + l*8 + i holds
// sig[r = rb*64 + h*32 + (l>>4)*8 + i][f = n*16 + (l&15)].
__global__ __launch_bounds__(256) void k_transpose(const float* __restrict__ sig,
                                                   __hip_bfloat16* __restrict__ sigT2)
{
  __shared__ float t[4096];                 // flat [r][f], XOR-swizzled banks
  const int tid = threadIdx.x;
  const float* sp = sig + (size_t)blockIdx.x * 4096;
  for (int idx = tid; idx < 4096; idx += 256) {
    int r = idx >> 6, f = idx & 63;
    t[(r << 6) + (f ^ ((r & 7) << 3))] = sp[idx];
  }
  __syncthreads();
  __hip_bfloat16* op = sigT2 + (size_t)blockIdx.x * 4096;
  for (int e = tid; e < 4096; e += 256) {
    int h = e >> 11, n = (e >> 9) & 3, l = (e >> 3) & 63, i = e & 7;
    int f = n * 16 + (l & 15);
    int r = h * 32 + (l >> 4) * 8 + i;
    op[e] = __float2bfloat16(t[(r << 6) + (f ^ ((r & 7) << 3))]);
  }
}

// ---------------- kernel 3 helpers ----------------------------------------------
template<int SB>
__device__ __forceinline__ void loadA4(const char* aw, int c_old, bf16x8* A) {
  #pragma unroll
  for (int i = 0; i < 4; ++i)
    if (c_old <= CACT_[SB + i])
      A[i] = *(const bf16x8*)(aw + (size_t)c_old * 16384 + (SB + i) * 1024);
}

template<int SB>
__device__ __forceinline__ void stepMFMA(int c_old, const bf16x8* A, const bf16x8* B,
                                         f32x4 (*acc)[4]) {
  __builtin_amdgcn_s_setprio(1);
  #pragma unroll
  for (int i = 3; i >= 0; --i) {
    if (c_old <= CACT_[SB + i]) {          // wave-uniform; static indices
      acc[i][0] = __builtin_amdgcn_mfma_f32_16x16x32_bf16(A[i], B[0], acc[i][0], 0, 0, 0);
      acc[i][1] = __builtin_amdgcn_mfma_f32_16x16x32_bf16(A[i], B[1], acc[i][1], 0, 0, 0);
      acc[i][2] = __builtin_amdgcn_mfma_f32_16x16x32_bf16(A[i], B[2], acc[i][2], 0, 0, 0);
      acc[i][3] = __builtin_amdgcn_mfma_f32_16x16x32_bf16(A[i], B[3], acc[i][3], 0, 0, 0);
    }
  }
  __builtin_amdgcn_s_setprio(0);
}

// One 4-scale pass. B comes from LDS (staged 16KB/super-chunk = 4 k-steps,
// double-buffered); A rolls from global with 2-buffer prefetch.
template<int SB>
__device__ __forceinline__ void run_pass(const char* aw, const char* sgb,
                                         short (*lbuf)[8192], int nsteps,
                                         int tid, int l, float* ob, int trow, int fl)
{
  f32x4 acc[4][4];
  const f32x4 z = {0.f, 0.f, 0.f, 0.f};
  #pragma unroll
  for (int i = 0; i < 4; ++i)
    #pragma unroll
    for (int n = 0; n < 4; ++n) acc[i][n] = z;

  const int nsc = (nsteps + 3) >> 2;

  auto stage = [&](int sc) {   // stages steps 4sc..4sc+3 (chunks 2sc+1, 2sc ascending)
    const char* gp = sgb - (size_t)(2 * sc + 1) * 8192 + tid * 16;
    char* lp = (char*)lbuf[sc & 1] + (tid >> 6) * 1024;
    #pragma unroll
    for (int it = 0; it < 4; ++it)
      __builtin_amdgcn_global_load_lds(
        (const __attribute__((address_space(1))) void*)(gp + it * 4096),
        (__attribute__((address_space(3))) void*)(lp + it * 4096), 16, 0, 0);
  };
  auto ldB = [&](int sc, int st, bf16x8* B) {
    const char* p = (const char*)lbuf[sc & 1] + (3 - (st & 3)) * 4096 + l * 16;
    #pragma unroll
    for (int n = 0; n < 4; ++n)
      B[n] = *(const bf16x8*)(p + n * 1024);
  };

  bf16x8 A0[4], A1[4], Ra[4], Rb[4];
  stage(0);
  loadA4<SB>(aw, 0, A0);
  loadA4<SB>(aw, 1, A1);
  __syncthreads();                        // stage(0) drained + all waves synced

  for (int sc = 0; sc < nsc; ++sc) {
    const int st = 4 * sc;
    if (sc + 1 < nsc) stage(sc + 1);      // overlaps this body's compute
    ldB(sc, st, Ra);
    if (st + 1 < nsteps) ldB(sc, st + 1, Rb);
    stepMFMA<SB>(st, A0, Ra, acc);
    loadA4<SB>(aw, st + 2, A0);
    if (st + 2 < nsteps) ldB(sc, st + 2, Ra);
    if (st + 1 < nsteps) stepMFMA<SB>(st + 1, A1, Rb, acc);
    loadA4<SB>(aw, st + 3, A1);
    if (st + 3 < nsteps) ldB(sc, st + 3, Rb);
    if (st + 2 < nsteps) stepMFMA<SB>(st + 2, A0, Ra, acc);
    loadA4<SB>(aw, st + 4, A0);           // next body's first steps
    if (st + 3 < nsteps) stepMFMA<SB>(st + 3, A1, Rb, acc);
    loadA4<SB>(aw, st + 5, A1);
    __syncthreads();                      // drains stage(sc+1) (already landed) + sync
  }

  #pragma unroll
  for (int i = 0; i < 4; ++i) {
    float* os = ob + (size_t)(SB + i) * SLEN * FEAT;
    #pragma unroll
    for (int n = 0; n < 4; ++n)
      #pragma unroll
      for (int r = 0; r < 4; ++r)
        os[(size_t)(trow + r) * FEAT + n * 16 + fl] = acc[i][n][r];
  }
}

// ---------------- kernel 3: banded-Toeplitz MFMA convolution --------------------
// Block = 256 thr = 4 waves; block owns (b, 64-t tile); wave tw owns rows t0+16tw..+15.
// B staged once per block into LDS (kills the 4x per-wave B redundancy);
// A global with rolling prefetch; two sequential 4-scale passes (3 waves/SIMD).
__global__ __launch_bounds__(256, 3) void k_wavelet_mfma(
    const __hip_bfloat16* __restrict__ sigT2,
    const __hip_bfloat16* __restrict__ atab,
    float* __restrict__ out)
{
  __shared__ __align__(16) short lbuf[2][8192];   // 2 x 16KB B super-chunks

  const int tid = threadIdx.x;
  const int bid = blockIdx.x;
  const int tt  = 63 - (bid >> 4);        // heavy (large t0) tiles first
  const int b   = bid & 15;
  const int t0  = tt * 64;
  const int tw  = tid >> 6;               // wave id
  const int l   = tid & 63;               // lane
  const int fl  = tid & 15;               // lane&15: A-row / B-col / D-col
  const int g   = (tid >> 4) & 3;         // lane>>4: k-group / D-row-group

  const int C = tt + 1;
  const char* aw  = (const char*)atab + tw * 8192 + (size_t)l * 16;
  const char* sgb = (const char*)sigT2 + (size_t)(b * 64 + tt) * 8192;

  float* ob = out + (size_t)b * NSC * SLEN * FEAT;
  const int trow = t0 + tw * 16 + g * 4;  // D row = 4*g + reg, col = 16n + fl

  run_pass<4>(aw, sgb, lbuf, 2 * C, tid, l, ob, trow, fl);           // scales 4-7
  run_pass<0>(aw, sgb, lbuf, min(2 * C, 14), tid, l, ob, trow, fl);  // scales 0-3
}

extern "C" void kernel_launch(void* const* d_in, const int* in_sizes, int n_in,
                              void* d_out, int out_size, void* d_ws, size_t ws_size,
                              hipStream_t stream) {
  const float* sig = (const float*)d_in[0];
  const float* mw  = (const float*)d_in[1];
  const float* sw  = (const float*)d_in[2];
  float*       out = (float*)d_out;

  // workspace: [0, ATAB_B) A-fragment table; sigT2 at 0x240000 (192KB guard gap
  // below sigT2 absorbs stage/load dangles for small tiles)
  __hip_bfloat16* atab  = (__hip_bfloat16*)d_ws;
  __hip_bfloat16* sigT2 = (__hip_bfloat16*)((char*)d_ws + 0x240000);

  WavP wp;
  const double lg = log10(64.0), st = lg / 7.0;
  for (int i = 0; i < NSC; ++i) {
    double y = (i == 7) ? lg : (double)i * st;
    double s = pow(10.0, y);
    wp.step[i] = (float)(63.0 / (double)(L_[i] - 1));
    wp.isq[i]  = (float)(1.0 / sqrt(s));
  }

  k_build_atab<<<NQ * 16, 256, 0, stream>>>(mw, sw, atab, wp);
  k_transpose<<<1024, 256, 0, stream>>>(sig, sigT2);
  k_wavelet_mfma<<<1024, 256, 0, stream>>>(sigT2, atab, out);
}